// Round 4
// baseline (92.459 us; speedup 1.0000x reference)
//
#include <hip/hip_runtime.h>

#define N_NODES 98304
#define N_EDGES 1572864
#define HIDDEN  64

#define NB    1536   // buckets (= N_NODES / 64), bucket = dst >> 6
#define BN    64     // nodes per bucket
#define NBLK  1536   // blocks in binning kernels
#define EPT   4      // edges per thread (1536*256*4 == N_EDGES exactly)
#define TPB   256

#define FP_SCALE 2097152.0f          // 2^21
#define FP_INV   (1.0f / 2097152.0f)

__device__ __forceinline__ float silu_f(float x) {
    return x / (1.0f + __expf(-x));
}

// ---------------- sorted path ----------------

// pack node data so the scatter gather is one float4 + one int
__global__ __launch_bounds__(TPB) void prep_kernel(const float* __restrict__ xr,
                                                   const float* __restrict__ xi,
                                                   const int* __restrict__ comm,
                                                   float4* __restrict__ node)
{
    const int n = blockIdx.x * TPB + threadIdx.x;
    if (n < N_NODES) {
        float4 v;
        v.x = xr[n];
        v.y = xi[n];
        v.z = __int_as_float(comm[n]);
        v.w = 0.0f;
        node[n] = v;
    }
}

__global__ __launch_bounds__(TPB) void hist_kernel(const int* __restrict__ ei,
                                                   unsigned short* __restrict__ histT)
{
    __shared__ unsigned hist[NB];
    const int tid = threadIdx.x, blk = blockIdx.x;
    for (int i = tid; i < NB; i += TPB) hist[i] = 0;
    __syncthreads();
    const int ebase = blk * (TPB * EPT);
#pragma unroll
    for (int k = 0; k < EPT; ++k) {
        const int d = ei[N_EDGES + ebase + k * TPB + tid];
        atomicAdd(&hist[(unsigned)d >> 6], 1u);
    }
    __syncthreads();
    for (int i = tid; i < NB; i += TPB)
        histT[(size_t)i * NBLK + blk] = (unsigned short)hist[i];
}

// one wave per bucket: exclusive scan (in place) of that bucket's 1536 block
// counts; bucket total out. 24 counts per lane.
__global__ __launch_bounds__(TPB) void scan_kernel(unsigned short* __restrict__ histT,
                                                   unsigned* __restrict__ totals)
{
    const int b = (blockIdx.x * TPB + threadIdx.x) >> 6;   // bucket = global wave id
    const int l = threadIdx.x & 63;
    unsigned short* row = histT + (size_t)b * NBLK;
    unsigned v[24];
    unsigned s = 0;
#pragma unroll
    for (int m = 0; m < 24; ++m) { v[m] = row[l * 24 + m]; s += v[m]; }
    unsigned p = s;
#pragma unroll
    for (int off = 1; off < 64; off <<= 1) {
        unsigned t = __shfl_up(p, off);
        if (l >= off) p += t;
    }
    unsigned excl = p - s;
#pragma unroll
    for (int m = 0; m < 24; ++m) { unsigned t = v[m]; row[l * 24 + m] = (unsigned short)excl; excl += t; }
    if (l == 63) totals[b] = p;
}

// single block: exclusive scan of the 1536 bucket totals -> bucket_base
__global__ __launch_bounds__(TPB) void scan2_kernel(const unsigned* __restrict__ totals,
                                                    unsigned* __restrict__ bucket_base)
{
    __shared__ unsigned wsum[4];
    const int tid = threadIdx.x, l = tid & 63, w = tid >> 6;
    unsigned v[6];
    unsigned s = 0;
#pragma unroll
    for (int m = 0; m < 6; ++m) { v[m] = totals[tid * 6 + m]; s += v[m]; }
    unsigned p = s;
#pragma unroll
    for (int off = 1; off < 64; off <<= 1) {
        unsigned t = __shfl_up(p, off);
        if (l >= off) p += t;
    }
    if (l == 63) wsum[w] = p;
    __syncthreads();
    unsigned wbase = 0;
    for (int i = 0; i < w; ++i) wbase += wsum[i];
    unsigned excl = wbase + (p - s);
#pragma unroll
    for (int m = 0; m < 6; ++m) { unsigned t = v[m]; bucket_base[tid * 6 + m] = excl; excl += t; }
}

// payload u64: [63:36]=dr(28b) [35:8]=di(28b) [7:2]=local node [1]=inter flag
__global__ __launch_bounds__(TPB) void scatter_kernel(const int* __restrict__ ei,
    const float* __restrict__ ew,
    const float4* __restrict__ node,
    const int* __restrict__ comm,
    const unsigned short* __restrict__ histT,
    const unsigned* __restrict__ bucket_base,
    unsigned long long* __restrict__ payload)
{
    __shared__ unsigned hist[NB];
    __shared__ unsigned baseS[NB];
    const int tid = threadIdx.x, blk = blockIdx.x;
    for (int i = tid; i < NB; i += TPB) hist[i] = 0;
    __syncthreads();
    const int ebase = blk * (TPB * EPT);
    unsigned long long pay[EPT];
    unsigned bq[EPT], rk[EPT];
#pragma unroll
    for (int k = 0; k < EPT; ++k) {
        const int e = ebase + k * TPB + tid;
        const int s = ei[e];
        const int d = ei[N_EDGES + e];
        const float w = ew[e];
        const float4 ns = node[s];
        const int cd = comm[d];
        const int dr = __float2int_rn(w * ns.x * FP_SCALE);
        const int di = __float2int_rn(w * ns.y * FP_SCALE);
        const unsigned flag = (__float_as_int(ns.z) == cd) ? 0u : 1u;
        const unsigned b = (unsigned)d >> 6;
        bq[k] = b;
        rk[k] = atomicAdd(&hist[b], 1u);
        pay[k] = ((unsigned long long)((unsigned)dr & 0x0FFFFFFFu) << 36)
               | ((unsigned long long)((unsigned)di & 0x0FFFFFFFu) << 8)
               | ((unsigned)(d & 63) << 2) | ((unsigned long long)flag << 1);
    }
    __syncthreads();
    for (int i = tid; i < NB; i += TPB)
        baseS[i] = bucket_base[i] + (unsigned)histT[(size_t)i * NBLK + blk];
    __syncthreads();
#pragma unroll
    for (int k = 0; k < EPT; ++k)
        payload[(size_t)(baseS[bq[k]] + rk[k])] = pay[k];
}

// one block per bucket: packed LDS accumulate + fused epilogue
__global__ __launch_bounds__(TPB) void accum_epilogue_kernel(
    const unsigned long long* __restrict__ payload,
    const unsigned* __restrict__ totals,
    const unsigned* __restrict__ bucket_base,
    const float* __restrict__ Wlr, const float* __restrict__ Wli,
    const float* __restrict__ Wgr, const float* __restrict__ Wgi,
    float4* __restrict__ out)
{
    __shared__ unsigned long long acc[BN * 2];  // [local node][intra/inter]
    __shared__ float2 wlr_s[32], wli_s[32], wgr_s[32], wgi_s[32];
    const int tid = threadIdx.x, b = blockIdx.x;
    if (tid < BN * 2) acc[tid] = 0ull;
    if (tid >= 128 && tid < 160) {
        const int h2 = tid - 128;
        wlr_s[h2] = ((const float2*)Wlr)[h2];
        wli_s[h2] = ((const float2*)Wli)[h2];
        wgr_s[h2] = ((const float2*)Wgr)[h2];
        wgi_s[h2] = ((const float2*)Wgi)[h2];
    }
    __syncthreads();
    const unsigned cnt = totals[b];
    const unsigned long long* buck = payload + bucket_base[b];
    for (unsigned i = tid; i < cnt; i += TPB) {
        const unsigned long long p = buck[i];
        const int dr = (int)((long long)p >> 36);
        const int di = (int)(((long long)(p << 28)) >> 36);
        const unsigned idx = (((unsigned)(p >> 2) & 63u) << 1) | ((unsigned)(p >> 1) & 1u);
        const unsigned long long delta =
            ((unsigned long long)(unsigned)dr << 32) + (unsigned long long)(unsigned)di;
        atomicAdd(&acc[idx], delta);
    }
    __syncthreads();
#pragma unroll
    for (int j = 0; j < 8; ++j) {
        const int idx = j * TPB + tid;   // 0..2047 = local node * 32 + h2
        const int ln  = idx >> 5;
        const int h2  = idx & 31;
        float sr_l, si_l, sr_g, si_g;
        {
            const unsigned long long U = acc[ln * 2 + 0];
            const int bi = (int)(unsigned)(U & 0xffffffffULL);
            const int ar = (int)(unsigned)(U >> 32) + (bi < 0 ? 1 : 0);
            sr_l = (float)ar * FP_INV; si_l = (float)bi * FP_INV;
        }
        {
            const unsigned long long U = acc[ln * 2 + 1];
            const int bi = (int)(unsigned)(U & 0xffffffffULL);
            const int ar = (int)(unsigned)(U >> 32) + (bi < 0 ? 1 : 0);
            sr_g = (float)ar * FP_INV; si_g = (float)bi * FP_INV;
        }
        const float2 a = wlr_s[h2], c = wli_s[h2], g = wgr_s[h2], f = wgi_s[h2];
        float4 o;
        {
            const float arl = a.x * sr_l - c.x * si_l;
            const float ail = c.x * sr_l + a.x * si_l;
            const float arg = g.x * sr_g - f.x * si_g;
            const float aig = f.x * sr_g + g.x * si_g;
            o.x = silu_f(arl) + silu_f(arg);
            o.y = silu_f(ail) + silu_f(aig);
        }
        {
            const float arl = a.y * sr_l - c.y * si_l;
            const float ail = c.y * sr_l + a.y * si_l;
            const float arg = g.y * sr_g - f.y * si_g;
            const float aig = f.y * sr_g + g.y * si_g;
            o.z = silu_f(arl) + silu_f(arg);
            o.w = silu_f(ail) + silu_f(aig);
        }
        out[(size_t)b * 2048 + idx] = o;
    }
}

// ---------------- fallback path (R2, used only if ws too small) ----------------

__global__ void edge_scatter_fb(const int* __restrict__ ei,
                                const float* __restrict__ ew,
                                const int* __restrict__ comm,
                                const float* __restrict__ xr,
                                const float* __restrict__ xi,
                                unsigned long long* __restrict__ P)
{
    const int e = blockIdx.x * blockDim.x + threadIdx.x;
    if (e >= N_EDGES) return;
    const int s = ei[e];
    const int d = ei[N_EDGES + e];
    const float w = ew[e];
    const int dr = __float2int_rn(w * xr[s] * FP_SCALE);
    const int di = __float2int_rn(w * xi[s] * FP_SCALE);
    const unsigned long long delta =
        (unsigned long long)(((long long)dr << 32) + (long long)di);
    const int base = (comm[s] == comm[d]) ? 0 : N_NODES;
    atomicAdd(&P[base + d], delta);
}

__global__ void epilogue_fb(const unsigned long long* __restrict__ P,
                            const float* __restrict__ Wlr,
                            const float* __restrict__ Wli,
                            const float* __restrict__ Wgr,
                            const float* __restrict__ Wgi,
                            float4* __restrict__ out)
{
    const int total = N_NODES * (HIDDEN / 2);
    const int t = blockIdx.x * blockDim.x + threadIdx.x;
    if (t >= total) return;
    const int n = t >> 5, h2 = t & 31;
    float sr_l, si_l, sr_g, si_g;
    {
        const unsigned long long U = P[n];
        const int bi = (int)(unsigned)(U & 0xffffffffULL);
        const int ar = (int)(unsigned)(U >> 32) + (bi < 0 ? 1 : 0);
        sr_l = (float)ar * FP_INV; si_l = (float)bi * FP_INV;
    }
    {
        const unsigned long long U = P[N_NODES + n];
        const int bi = (int)(unsigned)(U & 0xffffffffULL);
        const int ar = (int)(unsigned)(U >> 32) + (bi < 0 ? 1 : 0);
        sr_g = (float)ar * FP_INV; si_g = (float)bi * FP_INV;
    }
    const float2 wlr = ((const float2*)Wlr)[h2];
    const float2 wli = ((const float2*)Wli)[h2];
    const float2 wgr = ((const float2*)Wgr)[h2];
    const float2 wgi = ((const float2*)Wgi)[h2];
    float4 o;
    {
        const float arl = wlr.x * sr_l - wli.x * si_l;
        const float ail = wli.x * sr_l + wlr.x * si_l;
        const float arg = wgr.x * sr_g - wgi.x * si_g;
        const float aig = wgi.x * sr_g + wgr.x * si_g;
        o.x = silu_f(arl) + silu_f(arg);
        o.y = silu_f(ail) + silu_f(aig);
    }
    {
        const float arl = wlr.y * sr_l - wli.y * si_l;
        const float ail = wli.y * sr_l + wlr.y * si_l;
        const float arg = wgr.y * sr_g - wgi.y * si_g;
        const float aig = wgi.y * sr_g + wgr.y * si_g;
        o.z = silu_f(arl) + silu_f(arg);
        o.w = silu_f(ail) + silu_f(aig);
    }
    out[t] = o;
}

extern "C" void kernel_launch(void* const* d_in, const int* in_sizes, int n_in,
                              void* d_out, int out_size, void* d_ws, size_t ws_size,
                              hipStream_t stream) {
    const float* xr   = (const float*)d_in[0];
    const float* xi   = (const float*)d_in[1];
    const int*   ei   = (const int*)d_in[2];
    const float* ew   = (const float*)d_in[3];
    const int*   comm = (const int*)d_in[4];
    const float* Wlr  = (const float*)d_in[5];
    const float* Wli  = (const float*)d_in[6];
    const float* Wgr  = (const float*)d_in[7];
    const float* Wgi  = (const float*)d_in[8];

    const size_t payload_bytes = (size_t)N_EDGES * sizeof(unsigned long long);   // 12.58 MB
    const size_t hist_bytes    = (size_t)NB * NBLK * sizeof(unsigned short);     // 4.72 MB
    const size_t totals_bytes  = (size_t)NB * sizeof(unsigned);                  // 6 KB
    const size_t base_bytes    = (size_t)NB * sizeof(unsigned);                  // 6 KB
    const size_t node_bytes    = (size_t)N_NODES * sizeof(float4);               // 1.57 MB
    const size_t need = payload_bytes + hist_bytes + totals_bytes + base_bytes + node_bytes;

    if (ws_size >= need) {
        char* p = (char*)d_ws;
        unsigned long long* payload = (unsigned long long*)p;  p += payload_bytes;
        unsigned short* histT       = (unsigned short*)p;      p += hist_bytes;
        unsigned* totals            = (unsigned*)p;            p += totals_bytes;
        unsigned* bucket_base       = (unsigned*)p;            p += base_bytes;
        float4* node                = (float4*)p;

        hipLaunchKernelGGL(prep_kernel, dim3((N_NODES + TPB - 1) / TPB), dim3(TPB), 0, stream,
                           xr, xi, comm, node);
        hipLaunchKernelGGL(hist_kernel, dim3(NBLK), dim3(TPB), 0, stream, ei, histT);
        hipLaunchKernelGGL(scan_kernel, dim3(NB / 4), dim3(TPB), 0, stream, histT, totals);
        hipLaunchKernelGGL(scan2_kernel, dim3(1), dim3(TPB), 0, stream, totals, bucket_base);
        hipLaunchKernelGGL(scatter_kernel, dim3(NBLK), dim3(TPB), 0, stream,
                           ei, ew, node, comm, histT, bucket_base, payload);
        hipLaunchKernelGGL(accum_epilogue_kernel, dim3(NB), dim3(TPB), 0, stream,
                           payload, totals, bucket_base, Wlr, Wli, Wgr, Wgi, (float4*)d_out);
    } else {
        unsigned long long* P = (unsigned long long*)d_ws;
        hipMemsetAsync(P, 0, (size_t)2 * N_NODES * sizeof(unsigned long long), stream);
        hipLaunchKernelGGL(edge_scatter_fb, dim3((N_EDGES + 255) / 256), dim3(256), 0, stream,
                           ei, ew, comm, xr, xi, P);
        const int total = N_NODES * (HIDDEN / 2);
        hipLaunchKernelGGL(epilogue_fb, dim3((total + 255) / 256), dim3(256), 0, stream,
                           P, Wlr, Wli, Wgr, Wgi, (float4*)d_out);
    }
}

// Round 5
// 72.431 us; speedup vs baseline: 1.2765x; 1.2765x over previous
//
#include <hip/hip_runtime.h>

#define N_NODES 98304
#define N_EDGES 1572864
#define HIDDEN  64

#define NB      384      // buckets of 256 nodes; bucket = dst >> 8
#define BN      256      // nodes per bucket
#define NBLK    384      // edge-chunk blocks; CHUNK*NBLK == N_EDGES
#define CHUNK   4096     // edges per chunk
#define TPB_H   256
#define EPT_H   16       // 256*16 = 4096
#define TPB_S   512
#define EPT_S   8        // 512*8 = 4096
#define TPB_A   256

#define FP_SCALE 1048576.0f          // 2^20
#define FP_INV   (1.0f / 1048576.0f)

__device__ __forceinline__ float silu_f(float x) {
    return x / (1.0f + __expf(-x));
}

// ---------------- sorted path ----------------

// pack node data: one float4 gather per edge instead of xr+xi+comm
__global__ __launch_bounds__(TPB_H) void prep_kernel(const float* __restrict__ xr,
                                                     const float* __restrict__ xi,
                                                     const int* __restrict__ comm,
                                                     float4* __restrict__ node)
{
    const int n = blockIdx.x * TPB_H + threadIdx.x;
    if (n < N_NODES) {
        float4 v;
        v.x = xr[n];
        v.y = xi[n];
        v.z = __int_as_float(comm[n]);
        v.w = 0.0f;
        node[n] = v;
    }
}

__global__ __launch_bounds__(TPB_H) void hist_kernel(const int* __restrict__ ei,
                                                     unsigned short* __restrict__ histT)
{
    __shared__ unsigned hist[NB];
    const int tid = threadIdx.x, blk = blockIdx.x;
    for (int i = tid; i < NB; i += TPB_H) hist[i] = 0;
    __syncthreads();
    const int ebase = blk * CHUNK;
#pragma unroll
    for (int k = 0; k < EPT_H; ++k) {
        const int d = ei[N_EDGES + ebase + k * TPB_H + tid];
        atomicAdd(&hist[(unsigned)d >> 8], 1u);
    }
    __syncthreads();
    for (int i = tid; i < NB; i += TPB_H)
        histT[(size_t)i * NBLK + blk] = (unsigned short)hist[i];
}

// one wave per bucket: exclusive scan (in place) of that bucket's 384 block
// counts; bucket total out. 6 counts per lane.
__global__ __launch_bounds__(256) void scan_kernel(unsigned short* __restrict__ histT,
                                                   unsigned* __restrict__ totals)
{
    const int b = blockIdx.x * 4 + (threadIdx.x >> 6);
    const int l = threadIdx.x & 63;
    unsigned short* row = histT + (size_t)b * NBLK;
    unsigned v[6];
    unsigned s = 0;
#pragma unroll
    for (int m = 0; m < 6; ++m) { v[m] = row[l * 6 + m]; s += v[m]; }
    unsigned p = s;
#pragma unroll
    for (int off = 1; off < 64; off <<= 1) {
        unsigned t = __shfl_up(p, off);
        if (l >= off) p += t;
    }
    unsigned excl = p - s;
#pragma unroll
    for (int m = 0; m < 6; ++m) { unsigned t = v[m]; row[l * 6 + m] = (unsigned short)excl; excl += t; }
    if (l == 63) totals[b] = p;
}

// one wave: exclusive scan of the 384 bucket totals -> bucket_base
__global__ __launch_bounds__(64) void scan2_kernel(const unsigned* __restrict__ totals,
                                                   unsigned* __restrict__ bucket_base)
{
    const int l = threadIdx.x;
    unsigned v[6];
    unsigned s = 0;
#pragma unroll
    for (int m = 0; m < 6; ++m) { v[m] = totals[l * 6 + m]; s += v[m]; }
    unsigned p = s;
#pragma unroll
    for (int off = 1; off < 64; off <<= 1) {
        unsigned t = __shfl_up(p, off);
        if (l >= off) p += t;
    }
    unsigned excl = p - s;
#pragma unroll
    for (int m = 0; m < 6; ++m) { unsigned t = v[m]; bucket_base[l * 6 + m] = excl; excl += t; }
}

// payload u64: [63:37]=dr(27b) [36:10]=di(27b) [9:2]=local node(8b) [1]=inter flag
// Block-level counting sort in LDS, then bucket-ordered (mostly coalesced) copyout.
__global__ __launch_bounds__(TPB_S) void scatter_kernel(const int* __restrict__ ei,
    const float* __restrict__ ew,
    const float4* __restrict__ node,
    const int* __restrict__ comm,
    const unsigned short* __restrict__ histT,
    const unsigned* __restrict__ bucket_base,
    unsigned long long* __restrict__ payload)
{
    __shared__ unsigned long long sorted[CHUNK];   // 32 KB
    __shared__ unsigned short bucketOf[CHUNK];     // 8 KB
    __shared__ unsigned hist[NB];
    __shared__ unsigned localbase[NB];
    __shared__ unsigned baseS[NB];

    const int tid = threadIdx.x, blk = blockIdx.x;
    for (int i = tid; i < NB; i += TPB_S) hist[i] = 0;
    __syncthreads();

    const int ebase = blk * CHUNK;
    unsigned long long pay[EPT_S];
    unsigned pb[EPT_S], pr[EPT_S];
#pragma unroll
    for (int k = 0; k < EPT_S; ++k) {
        const int e = ebase + k * TPB_S + tid;
        const int s = ei[e];
        const int d = ei[N_EDGES + e];
        const float w = ew[e];
        const float4 ns = node[s];
        const int cd = comm[d];
        const int dr = __float2int_rn(w * ns.x * FP_SCALE);
        const int di = __float2int_rn(w * ns.y * FP_SCALE);
        const unsigned flag = (__float_as_int(ns.z) == cd) ? 0u : 1u;
        const unsigned b = (unsigned)d >> 8;
        pb[k] = b;
        pr[k] = atomicAdd(&hist[b], 1u);
        pay[k] = ((unsigned long long)((unsigned)dr & 0x07FFFFFFu) << 37)
               | ((unsigned long long)((unsigned)di & 0x07FFFFFFu) << 10)
               | ((unsigned)(d & 255) << 2) | ((unsigned long long)flag << 1);
    }
    __syncthreads();

    // wave 0: exclusive scan of block-local hist -> localbase
    if (tid < 64) {
        unsigned v[6];
        unsigned s = 0;
#pragma unroll
        for (int m = 0; m < 6; ++m) { v[m] = hist[tid * 6 + m]; s += v[m]; }
        unsigned p = s;
#pragma unroll
        for (int off = 1; off < 64; off <<= 1) {
            unsigned t = __shfl_up(p, off);
            if (tid >= off) p += t;
        }
        unsigned excl = p - s;
#pragma unroll
        for (int m = 0; m < 6; ++m) { unsigned t = v[m]; localbase[tid * 6 + m] = excl; excl += t; }
    }
    // all threads: global base for (this block, bucket)
    for (int i = tid; i < NB; i += TPB_S)
        baseS[i] = bucket_base[i] + (unsigned)histT[(size_t)i * NBLK + blk];
    __syncthreads();

    // place into bucket-sorted LDS order
#pragma unroll
    for (int k = 0; k < EPT_S; ++k) {
        const unsigned pos = localbase[pb[k]] + pr[k];
        sorted[pos] = pay[k];
        bucketOf[pos] = (unsigned short)pb[k];
    }
    __syncthreads();

    // bucket-ordered copyout: lane-contiguous, runs of ~10.7 entries per bucket
    for (int i = tid; i < CHUNK; i += TPB_S) {
        const unsigned b = bucketOf[i];
        payload[(size_t)(baseS[b] + ((unsigned)i - localbase[b]))] = sorted[i];
    }
}

// one block per bucket (256 nodes): packed LDS accumulate + fused epilogue
__global__ __launch_bounds__(TPB_A) void accum_epilogue_kernel(
    const unsigned long long* __restrict__ payload,
    const unsigned* __restrict__ totals,
    const unsigned* __restrict__ bucket_base,
    const float* __restrict__ Wlr, const float* __restrict__ Wli,
    const float* __restrict__ Wgr, const float* __restrict__ Wgi,
    float4* __restrict__ out)
{
    __shared__ unsigned long long acc[BN * 2];  // [local node][intra/inter], 4 KB
    __shared__ float2 wlr_s[32], wli_s[32], wgr_s[32], wgi_s[32];
    const int tid = threadIdx.x, b = blockIdx.x;
    acc[tid] = 0ull;
    acc[tid + 256] = 0ull;
    if (tid < 32) {
        wlr_s[tid] = ((const float2*)Wlr)[tid];
        wli_s[tid] = ((const float2*)Wli)[tid];
        wgr_s[tid] = ((const float2*)Wgr)[tid];
        wgi_s[tid] = ((const float2*)Wgi)[tid];
    }
    __syncthreads();
    const unsigned cnt = totals[b];
    const unsigned long long* buck = payload + bucket_base[b];
    for (unsigned i = tid; i < cnt; i += TPB_A) {
        const unsigned long long p = buck[i];
        const int dr = (int)((long long)p >> 37);
        const int di = (int)(((long long)(p << 27)) >> 37);
        const unsigned idx = (((unsigned)(p >> 2) & 255u) << 1) | ((unsigned)(p >> 1) & 1u);
        const unsigned long long delta =
            ((unsigned long long)(unsigned)dr << 32) + (unsigned long long)(unsigned)di;
        atomicAdd(&acc[idx], delta);
    }
    __syncthreads();
#pragma unroll
    for (int j = 0; j < 32; ++j) {
        const int idx = j * TPB_A + tid;   // 0..8191 = local node * 32 + h2
        const int ln  = idx >> 5;
        const int h2  = idx & 31;
        float sr_l, si_l, sr_g, si_g;
        {
            const unsigned long long U = acc[ln * 2 + 0];
            const int bi = (int)(unsigned)(U & 0xffffffffULL);
            const int ar = (int)(unsigned)(U >> 32) + (bi < 0 ? 1 : 0);
            sr_l = (float)ar * FP_INV; si_l = (float)bi * FP_INV;
        }
        {
            const unsigned long long U = acc[ln * 2 + 1];
            const int bi = (int)(unsigned)(U & 0xffffffffULL);
            const int ar = (int)(unsigned)(U >> 32) + (bi < 0 ? 1 : 0);
            sr_g = (float)ar * FP_INV; si_g = (float)bi * FP_INV;
        }
        const float2 a = wlr_s[h2], c = wli_s[h2], g = wgr_s[h2], f = wgi_s[h2];
        float4 o;
        {
            const float arl = a.x * sr_l - c.x * si_l;
            const float ail = c.x * sr_l + a.x * si_l;
            const float arg = g.x * sr_g - f.x * si_g;
            const float aig = f.x * sr_g + g.x * si_g;
            o.x = silu_f(arl) + silu_f(arg);
            o.y = silu_f(ail) + silu_f(aig);
        }
        {
            const float arl = a.y * sr_l - c.y * si_l;
            const float ail = c.y * sr_l + a.y * si_l;
            const float arg = g.y * sr_g - f.y * si_g;
            const float aig = f.y * sr_g + g.y * si_g;
            o.z = silu_f(arl) + silu_f(arg);
            o.w = silu_f(ail) + silu_f(aig);
        }
        out[(size_t)b * 8192 + idx] = o;
    }
}

// ---------------- fallback path (R2, used only if ws too small) ----------------

#define FB_SCALE 2097152.0f
#define FB_INV   (1.0f / 2097152.0f)

__global__ void edge_scatter_fb(const int* __restrict__ ei,
                                const float* __restrict__ ew,
                                const int* __restrict__ comm,
                                const float* __restrict__ xr,
                                const float* __restrict__ xi,
                                unsigned long long* __restrict__ P)
{
    const int e = blockIdx.x * blockDim.x + threadIdx.x;
    if (e >= N_EDGES) return;
    const int s = ei[e];
    const int d = ei[N_EDGES + e];
    const float w = ew[e];
    const int dr = __float2int_rn(w * xr[s] * FB_SCALE);
    const int di = __float2int_rn(w * xi[s] * FB_SCALE);
    const unsigned long long delta =
        (unsigned long long)(((long long)dr << 32) + (long long)di);
    const int base = (comm[s] == comm[d]) ? 0 : N_NODES;
    atomicAdd(&P[base + d], delta);
}

__global__ void epilogue_fb(const unsigned long long* __restrict__ P,
                            const float* __restrict__ Wlr,
                            const float* __restrict__ Wli,
                            const float* __restrict__ Wgr,
                            const float* __restrict__ Wgi,
                            float4* __restrict__ out)
{
    const int total = N_NODES * (HIDDEN / 2);
    const int t = blockIdx.x * blockDim.x + threadIdx.x;
    if (t >= total) return;
    const int n = t >> 5, h2 = t & 31;
    float sr_l, si_l, sr_g, si_g;
    {
        const unsigned long long U = P[n];
        const int bi = (int)(unsigned)(U & 0xffffffffULL);
        const int ar = (int)(unsigned)(U >> 32) + (bi < 0 ? 1 : 0);
        sr_l = (float)ar * FB_INV; si_l = (float)bi * FB_INV;
    }
    {
        const unsigned long long U = P[N_NODES + n];
        const int bi = (int)(unsigned)(U & 0xffffffffULL);
        const int ar = (int)(unsigned)(U >> 32) + (bi < 0 ? 1 : 0);
        sr_g = (float)ar * FB_INV; si_g = (float)bi * FB_INV;
    }
    const float2 wlr = ((const float2*)Wlr)[h2];
    const float2 wli = ((const float2*)Wli)[h2];
    const float2 wgr = ((const float2*)Wgr)[h2];
    const float2 wgi = ((const float2*)Wgi)[h2];
    float4 o;
    {
        const float arl = wlr.x * sr_l - wli.x * si_l;
        const float ail = wli.x * sr_l + wlr.x * si_l;
        const float arg = wgr.x * sr_g - wgi.x * si_g;
        const float aig = wgi.x * sr_g + wgr.x * si_g;
        o.x = silu_f(arl) + silu_f(arg);
        o.y = silu_f(ail) + silu_f(aig);
    }
    {
        const float arl = wlr.y * sr_l - wli.y * si_l;
        const float ail = wli.y * sr_l + wlr.y * si_l;
        const float arg = wgr.y * sr_g - wgi.y * si_g;
        const float aig = wgi.y * sr_g + wgr.y * si_g;
        o.z = silu_f(arl) + silu_f(arg);
        o.w = silu_f(ail) + silu_f(aig);
    }
    out[t] = o;
}

extern "C" void kernel_launch(void* const* d_in, const int* in_sizes, int n_in,
                              void* d_out, int out_size, void* d_ws, size_t ws_size,
                              hipStream_t stream) {
    const float* xr   = (const float*)d_in[0];
    const float* xi   = (const float*)d_in[1];
    const int*   ei   = (const int*)d_in[2];
    const float* ew   = (const float*)d_in[3];
    const int*   comm = (const int*)d_in[4];
    const float* Wlr  = (const float*)d_in[5];
    const float* Wli  = (const float*)d_in[6];
    const float* Wgr  = (const float*)d_in[7];
    const float* Wgi  = (const float*)d_in[8];

    const size_t payload_bytes = (size_t)N_EDGES * sizeof(unsigned long long);   // 12.58 MB
    const size_t hist_bytes    = (size_t)NB * NBLK * sizeof(unsigned short);     // 288 KB
    const size_t totals_bytes  = (size_t)NB * sizeof(unsigned);
    const size_t base_bytes    = (size_t)NB * sizeof(unsigned);
    const size_t node_bytes    = (size_t)N_NODES * sizeof(float4);               // 1.57 MB
    const size_t need = payload_bytes + hist_bytes + totals_bytes + base_bytes + node_bytes;

    if (ws_size >= need) {
        char* p = (char*)d_ws;
        unsigned long long* payload = (unsigned long long*)p;  p += payload_bytes;
        unsigned short* histT       = (unsigned short*)p;      p += hist_bytes;
        unsigned* totals            = (unsigned*)p;            p += totals_bytes;
        unsigned* bucket_base       = (unsigned*)p;            p += base_bytes;
        float4* node                = (float4*)p;

        hipLaunchKernelGGL(prep_kernel, dim3((N_NODES + TPB_H - 1) / TPB_H), dim3(TPB_H), 0, stream,
                           xr, xi, comm, node);
        hipLaunchKernelGGL(hist_kernel, dim3(NBLK), dim3(TPB_H), 0, stream, ei, histT);
        hipLaunchKernelGGL(scan_kernel, dim3(NB / 4), dim3(256), 0, stream, histT, totals);
        hipLaunchKernelGGL(scan2_kernel, dim3(1), dim3(64), 0, stream, totals, bucket_base);
        hipLaunchKernelGGL(scatter_kernel, dim3(NBLK), dim3(TPB_S), 0, stream,
                           ei, ew, node, comm, histT, bucket_base, payload);
        hipLaunchKernelGGL(accum_epilogue_kernel, dim3(NB), dim3(TPB_A), 0, stream,
                           payload, totals, bucket_base, Wlr, Wli, Wgr, Wgi, (float4*)d_out);
    } else {
        unsigned long long* P = (unsigned long long*)d_ws;
        hipMemsetAsync(P, 0, (size_t)2 * N_NODES * sizeof(unsigned long long), stream);
        hipLaunchKernelGGL(edge_scatter_fb, dim3((N_EDGES + 255) / 256), dim3(256), 0, stream,
                           ei, ew, comm, xr, xi, P);
        const int total = N_NODES * (HIDDEN / 2);
        hipLaunchKernelGGL(epilogue_fb, dim3((total + 255) / 256), dim3(256), 0, stream,
                           P, Wlr, Wli, Wgr, Wgi, (float4*)d_out);
    }
}